// Round 9
// baseline (1126.582 us; speedup 1.0000x reference)
//
#include <hip/hip_runtime.h>
#include <hip/hip_bf16.h>

// Problem constants (match reference setup_inputs)
#define N_USER 50000
#define N_ITEM 50000
#define NNODE  100000          // N_USER + N_ITEM
#define D_LAT  64
#define D_HID  256             // 4 * D_LAT
#define D_FEAT 1280
#define NXCD   8
#define NPX    (NNODE / NXCD)  // 12500 nodes per bucket
#define QCAP   525000          // per-bucket capacity

typedef __attribute__((ext_vector_type(8))) short    bf16x8;
typedef __attribute__((ext_vector_type(4))) float    f32x4;
typedef __attribute__((ext_vector_type(4))) float    float4v;

__device__ __forceinline__ unsigned short f2bf(float f) {
    unsigned u = __builtin_bit_cast(unsigned, f);
    u += 0x7FFFu + ((u >> 16) & 1u);          // round-to-nearest-even
    return (unsigned short)(u >> 16);
}
__device__ __forceinline__ float bf2f(unsigned short u) {
    return __builtin_bit_cast(float, ((unsigned)u) << 16);
}

// ---------------- phase A: bucket edges by dest range (read edges ONCE) ----------------
// entry = (c_local << 17) | r ; c_local < 12500 (14b), r < 100000 (17b)
__global__ void k_bucket(const int* __restrict__ rows, const int* __restrict__ cols,
                         int* __restrict__ qtail, unsigned* __restrict__ bq, int E) {
    __shared__ int bcnt[8];
    __shared__ int boff[8];
    __shared__ int gbase[8];
    __shared__ unsigned stage[1024];
    const int t = threadIdx.x;
    for (long base = (long)blockIdx.x * 1024; base < E; base += (long)gridDim.x * 1024) {
        if (t < 8) bcnt[t] = 0;
        __syncthreads();
        unsigned pk[4]; int bk[4]; int lo[4];
        #pragma unroll
        for (int j = 0; j < 4; ++j) {
            long i = base + t + j * 256;
            if (i < E) {
                int r = rows[i], c = cols[i];
                int b = c / NPX;
                pk[j] = ((unsigned)(c - b * NPX) << 17) | (unsigned)r;
                bk[j] = b;
                lo[j] = atomicAdd(&bcnt[b], 1);
            } else bk[j] = -1;
        }
        __syncthreads();
        if (t < 8) {
            int off = 0;
            for (int i = 0; i < t; ++i) off += bcnt[i];
            boff[t]  = off;
            gbase[t] = atomicAdd(&qtail[t], bcnt[t]);
        }
        __syncthreads();
        #pragma unroll
        for (int j = 0; j < 4; ++j)
            if (bk[j] >= 0) stage[boff[bk[j]] + lo[j]] = pk[j];
        __syncthreads();
        #pragma unroll 1
        for (int b = 0; b < 8; ++b) {
            int n = bcnt[b], ob = boff[b];
            unsigned* dst = bq + (size_t)b * QCAP + gbase[b];
            for (int k = t; k < n; k += 256) dst[k] = stage[ob + k];
        }
        __syncthreads();
    }
}

// ---------------- phase A.5: degree histogram from buckets (XCD-confined) ----------------
__global__ void k_count_from_bq(const int* __restrict__ qtail, const unsigned* __restrict__ bq,
                                int* __restrict__ cnt) {
    const int xcd   = blockIdx.x & 7;
    const int chunk = blockIdx.x >> 3;
    const int CB    = gridDim.x >> 3;
    const int n     = qtail[xcd];
    const unsigned* q = bq + (size_t)xcd * QCAP;
    const int base  = xcd * NPX;
    for (int i = chunk * 256 + threadIdx.x; i < n; i += CB * 256) {
        unsigned e = __builtin_nontemporal_load(q + i);
        atomicAdd(&cnt[base + (int)(e >> 17)], 1);
    }
}

__global__ void k_dinv(const int* __restrict__ cnt, float* __restrict__ dinv, int n) {
    int i = blockIdx.x * blockDim.x + threadIdx.x;
    if (i < n) {
        int c = cnt[i];
        dinv[i] = (c > 0) ? rsqrtf((float)c) : 0.0f;
    }
}

// ---------------- block scan (1024 elems / block of 256 threads) ----------------
__global__ void k_scan_block(const int* __restrict__ cnt, int* __restrict__ ptr1,
                             int* __restrict__ bsum, int n) {
    __shared__ int lds[256];
    const int base = blockIdx.x * 1024;
    const int t = threadIdx.x;
    const int idx = base + t * 4;
    int v0 = 0, v1 = 0, v2 = 0, v3 = 0;
    if (idx + 0 < n) v0 = cnt[idx + 0];
    if (idx + 1 < n) v1 = cnt[idx + 1];
    if (idx + 2 < n) v2 = cnt[idx + 2];
    if (idx + 3 < n) v3 = cnt[idx + 3];
    lds[t] = v0 + v1 + v2 + v3;
    __syncthreads();
    for (int off = 1; off < 256; off <<= 1) {
        int val = lds[t];
        int add = (t >= off) ? lds[t - off] : 0;
        __syncthreads();
        lds[t] = val + add;
        __syncthreads();
    }
    int run = (t == 0) ? 0 : lds[t - 1];
    if (t == 255) bsum[blockIdx.x] = lds[255];
    if (idx + 0 < n) { run += v0; ptr1[idx + 0] = run; }
    if (idx + 1 < n) { run += v1; ptr1[idx + 1] = run; }
    if (idx + 2 < n) { run += v2; ptr1[idx + 2] = run; }
    if (idx + 3 < n) { run += v3; ptr1[idx + 3] = run; }
}

__global__ void k_scan_top(int* __restrict__ bsum, int nb) {
    if (threadIdx.x == 0 && blockIdx.x == 0) {
        int acc = 0;
        for (int i = 0; i < nb; ++i) { int v = bsum[i]; bsum[i] = acc; acc += v; }
    }
}

__global__ void k_scan_apply(int* __restrict__ ptr1, int* __restrict__ cursor,
                             const int* __restrict__ cnt, const int* __restrict__ boff, int n) {
    int i = blockIdx.x * blockDim.x + threadIdx.x;
    if (i >= n) return;
    int f = ptr1[i] + boff[i >> 10];
    ptr1[i] = f;
    cursor[i] = f - cnt[i];
}

// ---------------- phase B: CSR scatter from buckets (XCD-confined, L2-resident) ----------------
__global__ void k_scatter_from_bq(const int* __restrict__ qtail, const unsigned* __restrict__ bq,
                                  int* __restrict__ cursor, int* __restrict__ adj_src) {
    const int xcd   = blockIdx.x & 7;
    const int chunk = blockIdx.x >> 3;
    const int CB    = gridDim.x >> 3;
    const int n     = qtail[xcd];
    const unsigned* q = bq + (size_t)xcd * QCAP;
    const int base  = xcd * NPX;
    for (int i = chunk * 256 + threadIdx.x; i < n; i += CB * 256) {
        unsigned e = __builtin_nontemporal_load(q + i);
        int c = base + (int)(e >> 17);
        int r = (int)(e & 0x1FFFFu);
        int pos = atomicAdd(&cursor[c], 1);
        adj_src[pos] = r;
    }
}

// ---------------- W transpose+cast: Wt[n][k] = bf16(W[k][n]) ----------------
__global__ void k_transpose_cast(const float* __restrict__ W, unsigned short* __restrict__ Wt,
                                 int K, int Nn) {
    int k = blockIdx.x * 256 + threadIdx.x;
    int n = blockIdx.y;
    if (k < K) Wt[(size_t)n * K + k] = f2bf(W[(size_t)k * Nn + n]);
}

// ---------------- GEMM1: wave-independent, barrier-free, LDS-free ----------------
// midb[row][col] = bf16( lrelu( A[row][:] . Bt[col][:] + b1[col] ) )
// One wave per 16 rows, all 256 cols. A fp32 from HBM, B bf16 from L1/L2.
__global__ __launch_bounds__(256, 3)
void k_gemm1_direct(const float* __restrict__ A, const unsigned short* __restrict__ Bt,
                    const float* __restrict__ bias, unsigned short* __restrict__ midb, int M) {
    const int lane = threadIdx.x & 63;
    const int gw   = (blockIdx.x * blockDim.x + threadIdx.x) >> 6;
    const int r0   = gw * 16;
    if (r0 >= M) return;
    const int l15  = lane & 15;
    const int q    = lane >> 4;
    const int koff = q * 8;
    const float*          Ap = A  + (size_t)(r0 + l15) * D_FEAT + koff;
    const unsigned short* Bp = Bt + (size_t)l15 * D_FEAT + koff;

    f32x4 acc[16] = {};

    float4v a0 = *(const float4v*)(Ap + 0);
    float4v a1 = *(const float4v*)(Ap + 4);
    for (int ki = 0; ki < D_FEAT / 32; ++ki) {
        const int k0 = ki * 32;
        float4v n0 = (float4v)0.0f, n1 = (float4v)0.0f;
        if (ki < D_FEAT / 32 - 1) {
            n0 = *(const float4v*)(Ap + k0 + 32);
            n1 = *(const float4v*)(Ap + k0 + 36);
        }
        bf16x8 av;
        av[0] = (short)f2bf(a0[0]); av[1] = (short)f2bf(a0[1]);
        av[2] = (short)f2bf(a0[2]); av[3] = (short)f2bf(a0[3]);
        av[4] = (short)f2bf(a1[0]); av[5] = (short)f2bf(a1[1]);
        av[6] = (short)f2bf(a1[2]); av[7] = (short)f2bf(a1[3]);
        #pragma unroll
        for (int fn = 0; fn < 16; ++fn) {
            bf16x8 bv = *(const bf16x8*)(Bp + (size_t)fn * 16 * D_FEAT + k0);
            acc[fn] = __builtin_amdgcn_mfma_f32_16x16x32_bf16(av, bv, acc[fn], 0, 0, 0);
        }
        a0 = n0; a1 = n1;
    }

    #pragma unroll
    for (int fn = 0; fn < 16; ++fn) {
        float bb = bias[fn * 16 + l15];
        #pragma unroll
        for (int reg = 0; reg < 4; ++reg) {
            int row = r0 + q * 4 + reg;
            float v = acc[fn][reg] + bb;
            v = (v > 0.0f) ? v : 0.01f * v;
            midb[(size_t)row * D_HID + fn * 16 + l15] = f2bf(v);
        }
    }
}

// ---------------- GEMM2 + fused row-normalize: wave-independent ----------------
// temp[row][:] = midb[row][:] @ W2t + b2 ; x/xb[N_USER+row][:] = normalize(temp)
__global__ __launch_bounds__(256)
void k_gemm2_direct(const unsigned short* __restrict__ midb, const unsigned short* __restrict__ W2t,
                    const float* __restrict__ bias, float* __restrict__ x,
                    unsigned short* __restrict__ xb, int M) {
    const int lane = threadIdx.x & 63;
    const int gw   = (blockIdx.x * blockDim.x + threadIdx.x) >> 6;
    const int r0   = gw * 16;
    if (r0 >= M) return;
    const int l15  = lane & 15;
    const int q    = lane >> 4;
    const int koff = q * 8;
    const unsigned short* Ap = midb + (size_t)(r0 + l15) * D_HID + koff;
    const unsigned short* Bp = W2t  + (size_t)l15 * D_HID + koff;

    f32x4 acc[4] = {};
    #pragma unroll
    for (int ki = 0; ki < D_HID / 32; ++ki) {
        bf16x8 av = *(const bf16x8*)(Ap + ki * 32);
        #pragma unroll
        for (int fn = 0; fn < 4; ++fn) {
            bf16x8 bv = *(const bf16x8*)(Bp + (size_t)fn * 16 * D_HID + ki * 32);
            acc[fn] = __builtin_amdgcn_mfma_f32_16x16x32_bf16(av, bv, acc[fn], 0, 0, 0);
        }
    }

    #pragma unroll
    for (int reg = 0; reg < 4; ++reg) {
        float o[4];
        float ss = 0.0f;
        #pragma unroll
        for (int fn = 0; fn < 4; ++fn) {
            o[fn] = acc[fn][reg] + bias[fn * 16 + l15];
            ss += o[fn] * o[fn];
        }
        ss += __shfl_xor(ss, 1, 64);
        ss += __shfl_xor(ss, 2, 64);
        ss += __shfl_xor(ss, 4, 64);
        ss += __shfl_xor(ss, 8, 64);
        float scale = 1.0f / fmaxf(sqrtf(ss), 1e-12f);
        int row = r0 + q * 4 + reg;
        size_t base = (size_t)(N_USER + row) * 64 + l15;
        #pragma unroll
        for (int fn = 0; fn < 4; ++fn) {
            float xv = o[fn] * scale;
            x[base + fn * 16]  = xv;
            xb[base + fn * 16] = f2bf(xv);
        }
    }
}

// ---------------- preference rows: normalize into x (fp32) + xb (bf16) ----------------
__global__ void k_norm_pref(const float* __restrict__ pref, float* __restrict__ x,
                            unsigned short* __restrict__ xb, int nrows) {
    int row  = blockIdx.x * (blockDim.x >> 6) + (threadIdx.x >> 6);
    int lane = threadIdx.x & 63;
    if (row >= nrows) return;
    long o = (long)row * 64 + lane;
    float v = pref[o];
    float ss = v * v;
    #pragma unroll
    for (int off = 32; off > 0; off >>= 1) ss += __shfl_xor(ss, off, 64);
    float scale = 1.0f / fmaxf(sqrtf(ss), 1e-12f);
    float xv = v * scale;
    x[o]  = xv;
    xb[o] = f2bf(xv);
}

// ---------------- conv1: s = x + h (in place), hb = bf16(h) ----------------
__global__ void k_conv1(const int* __restrict__ ptr, const int* __restrict__ adj_src,
                        const float* __restrict__ dinv, const unsigned short* __restrict__ xb,
                        float* __restrict__ x, unsigned short* __restrict__ hb, int n) {
    int node = blockIdx.x * (blockDim.x >> 6) + (threadIdx.x >> 6);
    int lane = threadIdx.x & 63;
    if (node >= n) return;
    int beg = ptr[node], end = ptr[node + 1];
    float acc = 0.0f;
    int j = beg;
    for (; j + 4 <= end; j += 4) {
        int s0 = adj_src[j + 0], s1 = adj_src[j + 1], s2 = adj_src[j + 2], s3 = adj_src[j + 3];
        float w0 = dinv[s0], w1 = dinv[s1], w2 = dinv[s2], w3 = dinv[s3];
        float x0 = bf2f(xb[(long)s0 * 64 + lane]);
        float x1 = bf2f(xb[(long)s1 * 64 + lane]);
        float x2 = bf2f(xb[(long)s2 * 64 + lane]);
        float x3 = bf2f(xb[(long)s3 * 64 + lane]);
        acc += w0 * x0 + w1 * x1 + w2 * x2 + w3 * x3;
    }
    for (; j < end; ++j) {
        int s0 = adj_src[j];
        acc += dinv[s0] * bf2f(xb[(long)s0 * 64 + lane]);
    }
    float hval = dinv[node] * acc;
    long o = (long)node * 64 + lane;
    x[o]  = x[o] + hval;          // s = x + h
    hb[o] = f2bf(hval);
}

// ---------------- conv2: out = s + D^-1/2 A D^-1/2 h ----------------
__global__ void k_conv2(const int* __restrict__ ptr, const int* __restrict__ adj_src,
                        const float* __restrict__ dinv, const unsigned short* __restrict__ hb,
                        const float* __restrict__ s, float* __restrict__ out, int n) {
    int node = blockIdx.x * (blockDim.x >> 6) + (threadIdx.x >> 6);
    int lane = threadIdx.x & 63;
    if (node >= n) return;
    int beg = ptr[node], end = ptr[node + 1];
    float acc = 0.0f;
    int j = beg;
    for (; j + 4 <= end; j += 4) {
        int s0 = adj_src[j + 0], s1 = adj_src[j + 1], s2 = adj_src[j + 2], s3 = adj_src[j + 3];
        float w0 = dinv[s0], w1 = dinv[s1], w2 = dinv[s2], w3 = dinv[s3];
        float x0 = bf2f(hb[(long)s0 * 64 + lane]);
        float x1 = bf2f(hb[(long)s1 * 64 + lane]);
        float x2 = bf2f(hb[(long)s2 * 64 + lane]);
        float x3 = bf2f(hb[(long)s3 * 64 + lane]);
        acc += w0 * x0 + w1 * x1 + w2 * x2 + w3 * x3;
    }
    for (; j < end; ++j) {
        int s0 = adj_src[j];
        acc += dinv[s0] * bf2f(hb[(long)s0 * 64 + lane]);
    }
    long o = (long)node * 64 + lane;
    out[o] = s[o] + dinv[node] * acc;
}

extern "C" void kernel_launch(void* const* d_in, const int* in_sizes, int n_in,
                              void* d_out, int out_size, void* d_ws, size_t ws_size,
                              hipStream_t stream) {
    const int*   edge_index = (const int*)d_in[1];
    const float* features   = (const float*)d_in[2];
    const float* preference = (const float*)d_in[3];
    const float* W1         = (const float*)d_in[4];
    const float* b1         = (const float*)d_in[5];
    const float* W2         = (const float*)d_in[6];
    const float* b2         = (const float*)d_in[7];

    const int E = in_sizes[1] / 2;                 // 4M directed edges
    const int* e_row = edge_index;
    const int* e_col = edge_index + E;

    // workspace layout (4-byte units)
    float* ws     = (float*)d_ws;
    float* x      = ws;                                    // NNODE*64 (x, then s=x+h)
    unsigned short* xb = (unsigned short*)(x + (size_t)NNODE * 64);   // NNODE*64 bf16
    unsigned short* hb = xb + (size_t)NNODE * 64;                     // NNODE*64 bf16
    float* dinv   = (float*)(hb + (size_t)NNODE * 64);     // NNODE
    int*   cnt    = (int*)(dinv + NNODE);                  // NNODE
    int*   ptr    = cnt + NNODE;                           // NNODE+1
    int*   cursor = ptr + NNODE + 1;                       // NNODE
    int*   bsum   = cursor + NNODE;                        // 128
    int*   qtail  = bsum + 128;                            // 8
    float* regionR = (float*)(qtail + 8);                  // shared region
    // MLP phase (dead after GEMM2):
    unsigned short* midb = (unsigned short*)regionR;                 // N_ITEM*256 bf16
    unsigned short* W1t  = midb + (size_t)N_ITEM * D_HID;            // 256*1280 bf16
    unsigned short* W2t  = W1t + (size_t)D_HID * D_FEAT;             // 64*256 bf16
    // Graph phase (overlays MLP phase):
    int*      adj_src = (int*)regionR;                     // E ints (16 MB)
    unsigned* bq      = (unsigned*)(adj_src + E);          // 8*QCAP uints (16.8 MB)

    float* out_xhat = (float*)d_out;                       // NNODE*64
    float* out_pref = (float*)d_out + (size_t)NNODE * 64;  // N_USER*64

    const int nscan_blocks = (NNODE + 1023) / 1024;        // 98

    // --- weight transpose + cast ---
    {
        dim3 g1((D_FEAT + 255) / 256, D_HID);
        k_transpose_cast<<<g1, 256, 0, stream>>>(W1, W1t, D_FEAT, D_HID);
        dim3 g2(1, D_LAT);
        k_transpose_cast<<<g2, 256, 0, stream>>>(W2, W2t, D_HID, D_LAT);
    }

    // --- GEMM1: midb = bf16(lrelu(features @ W1 + b1))  [50000 x 256] ---
    {
        int waves = N_ITEM / 16;                           // 3125
        k_gemm1_direct<<<(waves + 3) / 4, 256, 0, stream>>>(features, W1t, b1, midb, N_ITEM);
    }
    // --- GEMM2 + fused normalize: x[N_USER..], xb[N_USER..] ---
    {
        int waves = N_ITEM / 16;
        k_gemm2_direct<<<(waves + 3) / 4, 256, 0, stream>>>(midb, W2t, b2, x, xb, N_ITEM);
    }
    // --- preference rows: normalize into x + xb ---
    k_norm_pref<<<(N_USER + 3) / 4, 256, 0, stream>>>(preference, x, xb, N_USER);

    // --- edge pipeline (after GEMM2: regionR is free) ---
    hipMemsetAsync(qtail, 0, sizeof(int) * 8, stream);
    hipMemsetAsync(cnt, 0, sizeof(int) * NNODE, stream);
    hipMemsetAsync(ptr, 0, sizeof(int), stream);           // ptr[0] = 0

    k_bucket<<<1024, 256, 0, stream>>>(e_row, e_col, qtail, bq, E);
    k_count_from_bq<<<512, 256, 0, stream>>>(qtail, bq, cnt);
    k_dinv<<<(NNODE + 255) / 256, 256, 0, stream>>>(cnt, dinv, NNODE);
    k_scan_block<<<nscan_blocks, 256, 0, stream>>>(cnt, ptr + 1, bsum, NNODE);
    k_scan_top<<<1, 64, 0, stream>>>(bsum, nscan_blocks);
    k_scan_apply<<<(NNODE + 255) / 256, 256, 0, stream>>>(ptr + 1, cursor, cnt, bsum, NNODE);
    k_scatter_from_bq<<<512, 256, 0, stream>>>(qtail, bq, cursor, adj_src);

    // --- conv1: x <- x + h ; hb = bf16(h) ---
    k_conv1<<<(NNODE + 3) / 4, 256, 0, stream>>>(ptr, adj_src, dinv, xb, x, hb, NNODE);
    // --- conv2: out = (x + h) + conv(h) ---
    k_conv2<<<(NNODE + 3) / 4, 256, 0, stream>>>(ptr, adj_src, dinv, hb, x, out_xhat, NNODE);
    // --- preference passthrough ---
    hipMemcpyAsync(out_pref, preference, sizeof(float) * (size_t)N_USER * 64,
                   hipMemcpyDeviceToDevice, stream);
}

// Round 10
// 886.087 us; speedup vs baseline: 1.2714x; 1.2714x over previous
//
#include <hip/hip_runtime.h>
#include <hip/hip_bf16.h>

// Problem constants (match reference setup_inputs)
#define N_USER 50000
#define N_ITEM 50000
#define NNODE  100000          // N_USER + N_ITEM
#define D_LAT  64
#define D_HID  256             // 4 * D_LAT
#define D_FEAT 1280
#define NXCD   8
#define NODES_PER_XCD (NNODE / NXCD)   // 12500

typedef __attribute__((ext_vector_type(8))) short    bf16x8;
typedef __attribute__((ext_vector_type(4))) float    f32x4;
typedef __attribute__((ext_vector_type(4))) float    float4v;
typedef __attribute__((ext_vector_type(4))) unsigned short ushort4v;
typedef __attribute__((ext_vector_type(8))) unsigned short ushort8v;

__device__ __forceinline__ unsigned short f2bf(float f) {
    unsigned u = __builtin_bit_cast(unsigned, f);
    u += 0x7FFFu + ((u >> 16) & 1u);          // round-to-nearest-even
    return (unsigned short)(u >> 16);
}
__device__ __forceinline__ float bf2f(unsigned short u) {
    return __builtin_bit_cast(float, ((unsigned)u) << 16);
}

// ---------------- degree: XCD-confined histogram ----------------
__global__ void k_count_deg_x(const int* __restrict__ rows, int* __restrict__ cnt,
                              int E, int CH) {
    const int xcd   = blockIdx.x & 7;
    const int chunk = blockIdx.x >> 3;
    const int lo    = xcd * NODES_PER_XCD;
    const int hi    = lo + NODES_PER_XCD;
    const int beg   = chunk * CH;
    const int end   = min(beg + CH, E);
    for (int i = beg + threadIdx.x; i < end; i += 256) {
        int r = rows[i];
        if (r >= lo && r < hi) atomicAdd(&cnt[r], 1);
    }
}

__global__ void k_dinv(const int* __restrict__ cnt, float* __restrict__ dinv, int n) {
    int i = blockIdx.x * blockDim.x + threadIdx.x;
    if (i < n) {
        int c = cnt[i];
        dinv[i] = (c > 0) ? rsqrtf((float)c) : 0.0f;
    }
}

// ---------------- block scan (1024 elems / block of 256 threads) ----------------
__global__ void k_scan_block(const int* __restrict__ cnt, int* __restrict__ ptr1,
                             int* __restrict__ bsum, int n) {
    __shared__ int lds[256];
    const int base = blockIdx.x * 1024;
    const int t = threadIdx.x;
    const int idx = base + t * 4;
    int v0 = 0, v1 = 0, v2 = 0, v3 = 0;
    if (idx + 0 < n) v0 = cnt[idx + 0];
    if (idx + 1 < n) v1 = cnt[idx + 1];
    if (idx + 2 < n) v2 = cnt[idx + 2];
    if (idx + 3 < n) v3 = cnt[idx + 3];
    lds[t] = v0 + v1 + v2 + v3;
    __syncthreads();
    for (int off = 1; off < 256; off <<= 1) {
        int val = lds[t];
        int add = (t >= off) ? lds[t - off] : 0;
        __syncthreads();
        lds[t] = val + add;
        __syncthreads();
    }
    int run = (t == 0) ? 0 : lds[t - 1];
    if (t == 255) bsum[blockIdx.x] = lds[255];
    if (idx + 0 < n) { run += v0; ptr1[idx + 0] = run; }
    if (idx + 1 < n) { run += v1; ptr1[idx + 1] = run; }
    if (idx + 2 < n) { run += v2; ptr1[idx + 2] = run; }
    if (idx + 3 < n) { run += v3; ptr1[idx + 3] = run; }
}

__global__ void k_scan_top(int* __restrict__ bsum, int nb) {
    if (threadIdx.x == 0 && blockIdx.x == 0) {
        int acc = 0;
        for (int i = 0; i < nb; ++i) { int v = bsum[i]; bsum[i] = acc; acc += v; }
    }
}

__global__ void k_scan_apply(int* __restrict__ ptr1, int* __restrict__ cursor,
                             const int* __restrict__ cnt, const int* __restrict__ boff, int n) {
    int i = blockIdx.x * blockDim.x + threadIdx.x;
    if (i >= n) return;
    int f = ptr1[i] + boff[i >> 10];
    ptr1[i] = f;
    cursor[i] = f - cnt[i];
}

// ---------------- CSR build: XCD-confined scatter (src index only) ----------------
__global__ void k_build_adj_x(const int* __restrict__ rows, const int* __restrict__ cols,
                              int* __restrict__ cursor, int* __restrict__ adj_src,
                              int E, int CH) {
    const int xcd   = blockIdx.x & 7;
    const int chunk = blockIdx.x >> 3;
    const int lo    = xcd * NODES_PER_XCD;
    const int hi    = lo + NODES_PER_XCD;
    const int beg   = chunk * CH;
    const int end   = min(beg + CH, E);
    for (int i = beg + threadIdx.x; i < end; i += 256) {
        int c = cols[i];
        if (c >= lo && c < hi) {
            int pos = atomicAdd(&cursor[c], 1);
            adj_src[pos] = rows[i];
        }
    }
}

// ---------------- W transpose+cast: Wt[n][k] = bf16(W[k][n]) ----------------
__global__ void k_transpose_cast(const float* __restrict__ W, unsigned short* __restrict__ Wt,
                                 int K, int Nn) {
    int k = blockIdx.x * 256 + threadIdx.x;
    int n = blockIdx.y;
    if (k < K) Wt[(size_t)n * K + k] = f2bf(W[(size_t)k * Nn + n]);
}

// ---------------- GEMM1: BM=32 tile, 4 waves side-by-side in N, high occupancy ----------------
// midb[row][col] = bf16( lrelu( A[row][:] . Bt[col][:] + b1[col] ) ), A fp32 cast on stage.
__global__ __launch_bounds__(256, 6)
void k_gemm1_tile(const float* __restrict__ A, const unsigned short* __restrict__ Bt,
                  const float* __restrict__ bias, unsigned short* __restrict__ midb, int M) {
    constexpr int BM = 32;
    __shared__ __align__(16) char lds[BM * 128];   // 32 rows x 64 bf16 (XOR-swizzled) = 4 KB
    const int t    = threadIdx.x;
    const int lane = t & 63;
    const int wn   = t >> 6;            // wave covers cols wn*64..wn*64+63
    const int bm   = blockIdx.x * BM;
    const int l15  = lane & 15;
    const int q    = lane >> 4;

    f32x4 acc[2][4] = {};

    for (int k0 = 0; k0 < D_FEAT; k0 += 64) {
        // stage A tile [32][64] fp32 -> bf16 LDS; 512 float4s over 256 threads
        #pragma unroll
        for (int it = 0; it < 2; ++it) {
            int idx  = t + it * 256;        // 0..511
            int r    = idx >> 4;            // 0..31
            int kc   = (idx & 15) * 4;      // elem col 0..60
            int grow = bm + r;
            float4v v = (float4v)0.0f;
            if (grow < M) v = *(const float4v*)(A + (size_t)grow * D_FEAT + k0 + kc);
            ushort4v u;
            u[0] = f2bf(v[0]); u[1] = f2bf(v[1]); u[2] = f2bf(v[2]); u[3] = f2bf(v[3]);
            *(ushort4v*)(lds + ((r * 128 + kc * 2) ^ ((r & 7) << 4))) = u;
        }
        __syncthreads();
        #pragma unroll
        for (int ks = 0; ks < 2; ++ks) {
            bf16x8 a[2], b[4];
            #pragma unroll
            for (int fm = 0; fm < 2; ++fm) {
                int r = fm * 16 + l15;
                int byte = r * 128 + (ks * 32 + q * 8) * 2;
                a[fm] = *(const bf16x8*)(lds + (byte ^ ((r & 7) << 4)));
            }
            #pragma unroll
            for (int fn = 0; fn < 4; ++fn) {
                int col = wn * 64 + fn * 16 + l15;
                b[fn] = *(const bf16x8*)(Bt + (size_t)col * D_FEAT + k0 + ks * 32 + q * 8);
            }
            #pragma unroll
            for (int fm = 0; fm < 2; ++fm)
                #pragma unroll
                for (int fn = 0; fn < 4; ++fn)
                    acc[fm][fn] = __builtin_amdgcn_mfma_f32_16x16x32_bf16(a[fm], b[fn], acc[fm][fn], 0, 0, 0);
        }
        __syncthreads();
    }

    #pragma unroll
    for (int fm = 0; fm < 2; ++fm) {
        #pragma unroll
        for (int fn = 0; fn < 4; ++fn) {
            int colg = wn * 64 + fn * 16 + l15;
            float bb = bias[colg];
            #pragma unroll
            for (int reg = 0; reg < 4; ++reg) {
                int rowg = bm + fm * 16 + q * 4 + reg;
                if (rowg >= M) continue;
                float v = acc[fm][fn][reg] + bb;
                v = (v > 0.0f) ? v : 0.01f * v;
                midb[(size_t)rowg * D_HID + colg] = f2bf(v);
            }
        }
    }
}

// ---------------- GEMM2 + fused row-normalize (WM=4 waves stacked in M) ----------------
__global__ __launch_bounds__(256)
void k_gemm2_norm(const unsigned short* __restrict__ Araw, const unsigned short* __restrict__ Bt,
                  const float* __restrict__ bias, float* __restrict__ x,
                  unsigned short* __restrict__ xb, int M) {
    constexpr int BM = 256;
    __shared__ __align__(16) char lds[BM * 128];   // 256 rows x 64 bf16 (XOR-swizzled)
    const int t    = threadIdx.x;
    const int lane = t & 63;
    const int wm   = t >> 6;
    const int bm   = blockIdx.x * BM;
    const int l15  = lane & 15;
    const int q    = lane >> 4;

    f32x4 acc[4][4] = {};

    for (int k0 = 0; k0 < D_HID; k0 += 64) {
        #pragma unroll
        for (int p = 0; p < 4; ++p) {
            int c    = t + p * 256;
            int r    = c >> 2;
            int kc   = (c & 3) * 16;
            int grow = bm + r;
            int lb   = r * 128 + kc * 2;
            int swz  = (r & 7) << 4;
            ushort8v w0 = (ushort8v)0, w1 = (ushort8v)0;
            if (grow < M) {
                const unsigned short* Ar = Araw + (size_t)grow * D_HID + k0 + kc;
                w0 = *(const ushort8v*)(Ar);
                w1 = *(const ushort8v*)(Ar + 8);
            }
            *(ushort8v*)(lds + ((lb +  0) ^ swz)) = w0;
            *(ushort8v*)(lds + ((lb + 16) ^ swz)) = w1;
        }
        __syncthreads();
        #pragma unroll
        for (int ks = 0; ks < 2; ++ks) {
            bf16x8 a[4], b[4];
            #pragma unroll
            for (int fm = 0; fm < 4; ++fm) {
                int r = wm * 64 + fm * 16 + l15;
                int byte = r * 128 + (ks * 32 + q * 8) * 2;
                a[fm] = *(const bf16x8*)(lds + (byte ^ ((r & 7) << 4)));
            }
            #pragma unroll
            for (int fn = 0; fn < 4; ++fn) {
                int col = fn * 16 + l15;
                b[fn] = *(const bf16x8*)(Bt + (size_t)col * D_HID + k0 + ks * 32 + q * 8);
            }
            #pragma unroll
            for (int fm = 0; fm < 4; ++fm)
                #pragma unroll
                for (int fn = 0; fn < 4; ++fn)
                    acc[fm][fn] = __builtin_amdgcn_mfma_f32_16x16x32_bf16(a[fm], b[fn], acc[fm][fn], 0, 0, 0);
        }
        __syncthreads();
    }

    // fused normalize: each wave holds complete 64-wide rows
    #pragma unroll
    for (int fm = 0; fm < 4; ++fm) {
        float o[4][4];   // [fn][reg]
        #pragma unroll
        for (int fn = 0; fn < 4; ++fn) {
            float bb = bias[fn * 16 + l15];
            #pragma unroll
            for (int reg = 0; reg < 4; ++reg) o[fn][reg] = acc[fm][fn][reg] + bb;
        }
        #pragma unroll
        for (int reg = 0; reg < 4; ++reg) {
            float ss = o[0][reg] * o[0][reg] + o[1][reg] * o[1][reg]
                     + o[2][reg] * o[2][reg] + o[3][reg] * o[3][reg];
            ss += __shfl_xor(ss, 1, 64);
            ss += __shfl_xor(ss, 2, 64);
            ss += __shfl_xor(ss, 4, 64);
            ss += __shfl_xor(ss, 8, 64);
            float scale = 1.0f / fmaxf(sqrtf(ss), 1e-12f);
            int rowg = bm + wm * 64 + fm * 16 + q * 4 + reg;
            if (rowg >= M) continue;
            size_t base = (size_t)(N_USER + rowg) * 64 + l15;
            #pragma unroll
            for (int fn = 0; fn < 4; ++fn) {
                float xv = o[fn][reg] * scale;
                x[base + fn * 16]  = xv;
                xb[base + fn * 16] = f2bf(xv);
            }
        }
    }
}

// ---------------- preference rows: normalize into x (fp32) + xb (bf16) ----------------
__global__ void k_norm_pref(const float* __restrict__ pref, float* __restrict__ x,
                            unsigned short* __restrict__ xb, int nrows) {
    int row  = blockIdx.x * (blockDim.x >> 6) + (threadIdx.x >> 6);
    int lane = threadIdx.x & 63;
    if (row >= nrows) return;
    long o = (long)row * 64 + lane;
    float v = pref[o];
    float ss = v * v;
    #pragma unroll
    for (int off = 32; off > 0; off >>= 1) ss += __shfl_xor(ss, off, 64);
    float scale = 1.0f / fmaxf(sqrtf(ss), 1e-12f);
    float xv = v * scale;
    x[o]  = xv;
    xb[o] = f2bf(xv);
}

// ---------------- conv1: s = x + h (in place), hb = bf16(h) ----------------
__global__ void k_conv1(const int* __restrict__ ptr, const int* __restrict__ adj_src,
                        const float* __restrict__ dinv, const unsigned short* __restrict__ xb,
                        float* __restrict__ x, unsigned short* __restrict__ hb, int n) {
    int node = blockIdx.x * (blockDim.x >> 6) + (threadIdx.x >> 6);
    int lane = threadIdx.x & 63;
    if (node >= n) return;
    int beg = ptr[node], end = ptr[node + 1];
    float acc = 0.0f;
    int j = beg;
    for (; j + 4 <= end; j += 4) {
        int s0 = adj_src[j + 0], s1 = adj_src[j + 1], s2 = adj_src[j + 2], s3 = adj_src[j + 3];
        float w0 = dinv[s0], w1 = dinv[s1], w2 = dinv[s2], w3 = dinv[s3];
        float x0 = bf2f(xb[(long)s0 * 64 + lane]);
        float x1 = bf2f(xb[(long)s1 * 64 + lane]);
        float x2 = bf2f(xb[(long)s2 * 64 + lane]);
        float x3 = bf2f(xb[(long)s3 * 64 + lane]);
        acc += w0 * x0 + w1 * x1 + w2 * x2 + w3 * x3;
    }
    for (; j < end; ++j) acc += dinv[adj_src[j]] * bf2f(xb[(long)adj_src[j] * 64 + lane]);
    float hval = dinv[node] * acc;
    long o = (long)node * 64 + lane;
    x[o]  = x[o] + hval;          // s = x + h
    hb[o] = f2bf(hval);
}

// ---------------- conv2: out = s + D^-1/2 A D^-1/2 h ----------------
__global__ void k_conv2(const int* __restrict__ ptr, const int* __restrict__ adj_src,
                        const float* __restrict__ dinv, const unsigned short* __restrict__ hb,
                        const float* __restrict__ s, float* __restrict__ out, int n) {
    int node = blockIdx.x * (blockDim.x >> 6) + (threadIdx.x >> 6);
    int lane = threadIdx.x & 63;
    if (node >= n) return;
    int beg = ptr[node], end = ptr[node + 1];
    float acc = 0.0f;
    int j = beg;
    for (; j + 4 <= end; j += 4) {
        int s0 = adj_src[j + 0], s1 = adj_src[j + 1], s2 = adj_src[j + 2], s3 = adj_src[j + 3];
        float w0 = dinv[s0], w1 = dinv[s1], w2 = dinv[s2], w3 = dinv[s3];
        float x0 = bf2f(hb[(long)s0 * 64 + lane]);
        float x1 = bf2f(hb[(long)s1 * 64 + lane]);
        float x2 = bf2f(hb[(long)s2 * 64 + lane]);
        float x3 = bf2f(hb[(long)s3 * 64 + lane]);
        acc += w0 * x0 + w1 * x1 + w2 * x2 + w3 * x3;
    }
    for (; j < end; ++j) acc += dinv[adj_src[j]] * bf2f(hb[(long)adj_src[j] * 64 + lane]);
    long o = (long)node * 64 + lane;
    out[o] = s[o] + dinv[node] * acc;
}

extern "C" void kernel_launch(void* const* d_in, const int* in_sizes, int n_in,
                              void* d_out, int out_size, void* d_ws, size_t ws_size,
                              hipStream_t stream) {
    const int*   edge_index = (const int*)d_in[1];
    const float* features   = (const float*)d_in[2];
    const float* preference = (const float*)d_in[3];
    const float* W1         = (const float*)d_in[4];
    const float* b1         = (const float*)d_in[5];
    const float* W2         = (const float*)d_in[6];
    const float* b2         = (const float*)d_in[7];

    const int E = in_sizes[1] / 2;                 // 4M directed edges
    const int* e_row = edge_index;
    const int* e_col = edge_index + E;

    // workspace layout (4-byte units)
    float* ws     = (float*)d_ws;
    float* x      = ws;                                    // NNODE*64 (x, then s=x+h)
    unsigned short* xb = (unsigned short*)(x + (size_t)NNODE * 64);   // NNODE*64 bf16
    unsigned short* hb = xb + (size_t)NNODE * 64;                     // NNODE*64 bf16
    float* dinv   = (float*)(hb + (size_t)NNODE * 64);     // NNODE
    int*   cnt    = (int*)(dinv + NNODE);                  // NNODE
    int*   ptr    = cnt + NNODE;                           // NNODE+1
    int*   cursor = ptr + NNODE + 1;                       // NNODE
    int*   bsum   = cursor + NNODE;                        // 128
    float* regionR = (float*)(bsum + 128);                 // shared region
    // MLP phase (dead after GEMM2):
    unsigned short* midb = (unsigned short*)regionR;                 // N_ITEM*256 bf16
    unsigned short* W1t  = midb + (size_t)N_ITEM * D_HID;            // 256*1280 bf16
    unsigned short* W2t  = W1t + (size_t)D_HID * D_FEAT;             // 64*256 bf16
    // Graph phase (overlays MLP phase):
    int*   adj_src = (int*)regionR;                        // E

    float* out_xhat = (float*)d_out;                       // NNODE*64
    float* out_pref = (float*)d_out + (size_t)NNODE * 64;  // N_USER*64

    const int nscan_blocks = (NNODE + 1023) / 1024;        // 98
    const int nchunks = 256;
    const int CH = (E + nchunks - 1) / nchunks;            // edges per chunk

    // --- degree / dinv (XCD-confined histogram) ---
    hipMemsetAsync(cnt, 0, sizeof(int) * NNODE, stream);
    k_count_deg_x<<<nchunks * NXCD, 256, 0, stream>>>(e_row, cnt, E, CH);
    k_dinv<<<(NNODE + 255) / 256, 256, 0, stream>>>(cnt, dinv, NNODE);

    // --- weight transpose + cast ---
    {
        dim3 g1((D_FEAT + 255) / 256, D_HID);
        k_transpose_cast<<<g1, 256, 0, stream>>>(W1, W1t, D_FEAT, D_HID);
        dim3 g2(1, D_LAT);
        k_transpose_cast<<<g2, 256, 0, stream>>>(W2, W2t, D_HID, D_LAT);
    }

    // --- GEMM1: midb = bf16(lrelu(features @ W1 + b1))  [50000 x 256], BM=32 tiles ---
    k_gemm1_tile<<<(N_ITEM + 31) / 32, 256, 0, stream>>>(features, W1t, b1, midb, N_ITEM);

    // --- GEMM2 + fused normalize: x[N_USER..], xb[N_USER..] ---
    k_gemm2_norm<<<(N_ITEM + 255) / 256, 256, 0, stream>>>(midb, W2t, b2, x, xb, N_ITEM);

    // --- preference rows: normalize into x + xb ---
    k_norm_pref<<<(N_USER + 3) / 4, 256, 0, stream>>>(preference, x, xb, N_USER);

    // --- CSR build ---
    hipMemsetAsync(ptr, 0, sizeof(int), stream);           // ptr[0] = 0
    k_scan_block<<<nscan_blocks, 256, 0, stream>>>(cnt, ptr + 1, bsum, NNODE);
    k_scan_top<<<1, 64, 0, stream>>>(bsum, nscan_blocks);
    k_scan_apply<<<(NNODE + 255) / 256, 256, 0, stream>>>(ptr + 1, cursor, cnt, bsum, NNODE);
    k_build_adj_x<<<nchunks * NXCD, 256, 0, stream>>>(e_row, e_col, cursor, adj_src, E, CH);

    // --- conv1: x <- x + h ; hb = bf16(h) ---
    k_conv1<<<(NNODE + 3) / 4, 256, 0, stream>>>(ptr, adj_src, dinv, xb, x, hb, NNODE);
    // --- conv2: out = (x + h) + conv(h) ---
    k_conv2<<<(NNODE + 3) / 4, 256, 0, stream>>>(ptr, adj_src, dinv, hb, x, out_xhat, NNODE);
    // --- preference passthrough ---
    hipMemcpyAsync(out_pref, preference, sizeof(float) * (size_t)N_USER * 64,
                   hipMemcpyDeviceToDevice, stream);
}

// Round 11
// 821.719 us; speedup vs baseline: 1.3710x; 1.0783x over previous
//
#include <hip/hip_runtime.h>
#include <hip/hip_bf16.h>

// Problem constants (match reference setup_inputs)
#define N_USER 50000
#define N_ITEM 50000
#define NNODE  100000          // N_USER + N_ITEM
#define D_LAT  64
#define D_HID  256             // 4 * D_LAT
#define D_FEAT 1280
#define NXCD   8
#define NODES_PER_XCD (NNODE / NXCD)   // 12500

typedef __attribute__((ext_vector_type(8))) short    bf16x8;
typedef __attribute__((ext_vector_type(4))) float    f32x4;
typedef __attribute__((ext_vector_type(4))) float    float4v;
typedef __attribute__((ext_vector_type(4))) unsigned short ushort4v;
typedef __attribute__((ext_vector_type(8))) unsigned short ushort8v;

__device__ __forceinline__ unsigned short f2bf(float f) {
    unsigned u = __builtin_bit_cast(unsigned, f);
    u += 0x7FFFu + ((u >> 16) & 1u);          // round-to-nearest-even
    return (unsigned short)(u >> 16);
}
__device__ __forceinline__ float bf2f(unsigned short u) {
    return __builtin_bit_cast(float, ((unsigned)u) << 16);
}

// ---------------- degree: XCD-confined histogram (nt on the edge stream) ----------------
__global__ void k_count_deg_x(const int* __restrict__ rows, int* __restrict__ cnt,
                              int E, int CH) {
    const int xcd   = blockIdx.x & 7;
    const int chunk = blockIdx.x >> 3;
    const int lo    = xcd * NODES_PER_XCD;
    const int hi    = lo + NODES_PER_XCD;
    const int beg   = chunk * CH;
    const int end   = min(beg + CH, E);
    for (int i = beg + threadIdx.x; i < end; i += 256) {
        int r = __builtin_nontemporal_load(rows + i);
        if (r >= lo && r < hi) atomicAdd(&cnt[r], 1);
    }
}

__global__ void k_dinv(const int* __restrict__ cnt, float* __restrict__ dinv, int n) {
    int i = blockIdx.x * blockDim.x + threadIdx.x;
    if (i < n) {
        int c = cnt[i];
        dinv[i] = (c > 0) ? rsqrtf((float)c) : 0.0f;
    }
}

// ---------------- block scan (1024 elems / block of 256 threads) ----------------
__global__ void k_scan_block(const int* __restrict__ cnt, int* __restrict__ ptr1,
                             int* __restrict__ bsum, int n) {
    __shared__ int lds[256];
    const int base = blockIdx.x * 1024;
    const int t = threadIdx.x;
    const int idx = base + t * 4;
    int v0 = 0, v1 = 0, v2 = 0, v3 = 0;
    if (idx + 0 < n) v0 = cnt[idx + 0];
    if (idx + 1 < n) v1 = cnt[idx + 1];
    if (idx + 2 < n) v2 = cnt[idx + 2];
    if (idx + 3 < n) v3 = cnt[idx + 3];
    lds[t] = v0 + v1 + v2 + v3;
    __syncthreads();
    for (int off = 1; off < 256; off <<= 1) {
        int val = lds[t];
        int add = (t >= off) ? lds[t - off] : 0;
        __syncthreads();
        lds[t] = val + add;
        __syncthreads();
    }
    int run = (t == 0) ? 0 : lds[t - 1];
    if (t == 255) bsum[blockIdx.x] = lds[255];
    if (idx + 0 < n) { run += v0; ptr1[idx + 0] = run; }
    if (idx + 1 < n) { run += v1; ptr1[idx + 1] = run; }
    if (idx + 2 < n) { run += v2; ptr1[idx + 2] = run; }
    if (idx + 3 < n) { run += v3; ptr1[idx + 3] = run; }
}

__global__ void k_scan_top(int* __restrict__ bsum, int nb) {
    if (threadIdx.x == 0 && blockIdx.x == 0) {
        int acc = 0;
        for (int i = 0; i < nb; ++i) { int v = bsum[i]; bsum[i] = acc; acc += v; }
    }
}

__global__ void k_scan_apply(int* __restrict__ ptr1, int* __restrict__ cursor,
                             const int* __restrict__ cnt, const int* __restrict__ boff, int n) {
    int i = blockIdx.x * blockDim.x + threadIdx.x;
    if (i >= n) return;
    int f = ptr1[i] + boff[i >> 10];
    ptr1[i] = f;
    cursor[i] = f - cnt[i];
}

// ---------------- CSR build: XCD-confined scatter (nt on the edge streams) ----------------
__global__ void k_build_adj_x(const int* __restrict__ rows, const int* __restrict__ cols,
                              int* __restrict__ cursor, int* __restrict__ adj_src,
                              int E, int CH) {
    const int xcd   = blockIdx.x & 7;
    const int chunk = blockIdx.x >> 3;
    const int lo    = xcd * NODES_PER_XCD;
    const int hi    = lo + NODES_PER_XCD;
    const int beg   = chunk * CH;
    const int end   = min(beg + CH, E);
    for (int i = beg + threadIdx.x; i < end; i += 256) {
        int c = __builtin_nontemporal_load(cols + i);
        if (c >= lo && c < hi) {
            int r = __builtin_nontemporal_load(rows + i);
            int pos = atomicAdd(&cursor[c], 1);
            adj_src[pos] = r;
        }
    }
}

// ---------------- W transpose+cast: Wt[n][k] = bf16(W[k][n]) ----------------
__global__ void k_transpose_cast(const float* __restrict__ W, unsigned short* __restrict__ Wt,
                                 int K, int Nn) {
    int k = blockIdx.x * 256 + threadIdx.x;
    int n = blockIdx.y;
    if (k < K) Wt[(size_t)n * K + k] = f2bf(W[(size_t)k * Nn + n]);
}

// ---------------- bf16 MFMA GEMM (r6-proven version) ----------------
// C[row][col] = act( sum_k A[row][k] * Bt[col][k] + bias[col] )
// NORM: row-normalize epilogue (requires WN==1), writes fp32 C and bf16 xbOut.
template<int WM, int WN, bool AF32, bool LRELU, bool OUTBF16, bool NORM>
__global__ __launch_bounds__(256)
void k_mfma_gemm(const void* __restrict__ Araw, const unsigned short* __restrict__ Bt,
                 const float* __restrict__ bias, void* __restrict__ Craw,
                 unsigned short* __restrict__ xbOut,
                 int M, int K, int ldc, int row_off) {
    constexpr int BM = WM * 64;
    __shared__ __align__(16) char lds[BM * 128];   // BM rows x 64 bf16 (XOR-swizzled)
    const int t    = threadIdx.x;
    const int lane = t & 63;
    const int wave = t >> 6;
    const int wm   = (WN == 1) ? wave : 0;
    const int wn   = (WN == 1) ? 0 : wave;
    const int bm   = blockIdx.x * BM;

    f32x4 acc[4][4] = {};

    for (int k0 = 0; k0 < K; k0 += 64) {
        #pragma unroll
        for (int p = 0; p < WM; ++p) {
            int c    = t + p * 256;
            int r    = c >> 2;              // 0..BM-1
            int kc   = (c & 3) * 16;        // elem offset in BK
            int grow = bm + r;
            int lb   = r * 128 + kc * 2;    // byte offset
            int swz  = (r & 7) << 4;
            if (AF32) {
                const float* Ar = (const float*)Araw + (size_t)grow * K + k0 + kc;
                #pragma unroll
                for (int j = 0; j < 4; ++j) {
                    float4v v = (float4v)0.0f;
                    if (grow < M) v = *(const float4v*)(Ar + j * 4);
                    ushort4v u;
                    u[0] = f2bf(v[0]); u[1] = f2bf(v[1]);
                    u[2] = f2bf(v[2]); u[3] = f2bf(v[3]);
                    *(ushort4v*)(lds + ((lb + j * 8) ^ swz)) = u;
                }
            } else {
                const unsigned short* Ar = (const unsigned short*)Araw + (size_t)grow * K + k0 + kc;
                ushort8v w0 = (ushort8v)0, w1 = (ushort8v)0;
                if (grow < M) {
                    w0 = *(const ushort8v*)(Ar);
                    w1 = *(const ushort8v*)(Ar + 8);
                }
                *(ushort8v*)(lds + ((lb +  0) ^ swz)) = w0;
                *(ushort8v*)(lds + ((lb + 16) ^ swz)) = w1;
            }
        }
        __syncthreads();
        #pragma unroll
        for (int ks = 0; ks < 2; ++ks) {
            bf16x8 a[4], b[4];
            #pragma unroll
            for (int fm = 0; fm < 4; ++fm) {
                int r = wm * 64 + fm * 16 + (lane & 15);
                int byte = r * 128 + (ks * 32 + (lane >> 4) * 8) * 2;
                a[fm] = *(const bf16x8*)(lds + (byte ^ ((r & 7) << 4)));
            }
            #pragma unroll
            for (int fn = 0; fn < 4; ++fn) {
                int col = wn * 64 + fn * 16 + (lane & 15);
                b[fn] = *(const bf16x8*)(Bt + (size_t)col * K + k0 + ks * 32 + (lane >> 4) * 8);
            }
            #pragma unroll
            for (int fm = 0; fm < 4; ++fm)
                #pragma unroll
                for (int fn = 0; fn < 4; ++fn)
                    acc[fm][fn] = __builtin_amdgcn_mfma_f32_16x16x32_bf16(a[fm], b[fn], acc[fm][fn], 0, 0, 0);
        }
        __syncthreads();
    }

    if (NORM) {
        #pragma unroll
        for (int fm = 0; fm < 4; ++fm) {
            float o[4][4];   // [fn][reg]
            #pragma unroll
            for (int fn = 0; fn < 4; ++fn) {
                float bb = bias[fn * 16 + (lane & 15)];
                #pragma unroll
                for (int reg = 0; reg < 4; ++reg) o[fn][reg] = acc[fm][fn][reg] + bb;
            }
            #pragma unroll
            for (int reg = 0; reg < 4; ++reg) {
                float ss = o[0][reg] * o[0][reg] + o[1][reg] * o[1][reg]
                         + o[2][reg] * o[2][reg] + o[3][reg] * o[3][reg];
                ss += __shfl_xor(ss, 1, 64);
                ss += __shfl_xor(ss, 2, 64);
                ss += __shfl_xor(ss, 4, 64);
                ss += __shfl_xor(ss, 8, 64);
                float scale = 1.0f / fmaxf(sqrtf(ss), 1e-12f);
                int rowg = bm + wm * 64 + fm * 16 + (lane >> 4) * 4 + reg;
                if (rowg >= M) continue;
                size_t base = (size_t)(row_off + rowg) * 64 + (lane & 15);
                #pragma unroll
                for (int fn = 0; fn < 4; ++fn) {
                    float xv = o[fn][reg] * scale;
                    ((float*)Craw)[base + fn * 16] = xv;
                    xbOut[base + fn * 16] = f2bf(xv);
                }
            }
        }
    } else {
        #pragma unroll
        for (int fm = 0; fm < 4; ++fm) {
            #pragma unroll
            for (int fn = 0; fn < 4; ++fn) {
                int colg = wn * 64 + fn * 16 + (lane & 15);
                float bb = bias[colg];
                #pragma unroll
                for (int reg = 0; reg < 4; ++reg) {
                    int rowg = bm + wm * 64 + fm * 16 + (lane >> 4) * 4 + reg;
                    if (rowg >= M) continue;
                    float v = acc[fm][fn][reg] + bb;
                    if (LRELU) v = (v > 0.0f) ? v : 0.01f * v;
                    if (OUTBF16) {
                        ((unsigned short*)Craw)[(size_t)(row_off + rowg) * ldc + colg] = f2bf(v);
                    } else {
                        ((float*)Craw)[(size_t)(row_off + rowg) * ldc + colg] = v;
                    }
                }
            }
        }
    }
}

// ---------------- preference rows: normalize into x (fp32) + xb (bf16) ----------------
__global__ void k_norm_pref(const float* __restrict__ pref, float* __restrict__ x,
                            unsigned short* __restrict__ xb, int nrows) {
    int row  = blockIdx.x * (blockDim.x >> 6) + (threadIdx.x >> 6);
    int lane = threadIdx.x & 63;
    if (row >= nrows) return;
    long o = (long)row * 64 + lane;
    float v = pref[o];
    float ss = v * v;
    #pragma unroll
    for (int off = 32; off > 0; off >>= 1) ss += __shfl_xor(ss, off, 64);
    float scale = 1.0f / fmaxf(sqrtf(ss), 1e-12f);
    float xv = v * scale;
    x[o]  = xv;
    xb[o] = f2bf(xv);
}

// ---------------- conv1: s = x + h (in place), hb = bf16(h) ----------------
__global__ void k_conv1(const int* __restrict__ ptr, const int* __restrict__ adj_src,
                        const float* __restrict__ dinv, const unsigned short* __restrict__ xb,
                        float* __restrict__ x, unsigned short* __restrict__ hb, int n) {
    int node = blockIdx.x * (blockDim.x >> 6) + (threadIdx.x >> 6);
    int lane = threadIdx.x & 63;
    if (node >= n) return;
    int beg = ptr[node], end = ptr[node + 1];
    float acc = 0.0f;
    int j = beg;
    for (; j + 4 <= end; j += 4) {
        int s0 = adj_src[j + 0], s1 = adj_src[j + 1], s2 = adj_src[j + 2], s3 = adj_src[j + 3];
        float w0 = dinv[s0], w1 = dinv[s1], w2 = dinv[s2], w3 = dinv[s3];
        float x0 = bf2f(xb[(long)s0 * 64 + lane]);
        float x1 = bf2f(xb[(long)s1 * 64 + lane]);
        float x2 = bf2f(xb[(long)s2 * 64 + lane]);
        float x3 = bf2f(xb[(long)s3 * 64 + lane]);
        acc += w0 * x0 + w1 * x1 + w2 * x2 + w3 * x3;
    }
    for (; j < end; ++j) acc += dinv[adj_src[j]] * bf2f(xb[(long)adj_src[j] * 64 + lane]);
    float hval = dinv[node] * acc;
    long o = (long)node * 64 + lane;
    x[o]  = x[o] + hval;          // s = x + h
    hb[o] = f2bf(hval);
}

// ---------------- conv2: out = s + D^-1/2 A D^-1/2 h ----------------
__global__ void k_conv2(const int* __restrict__ ptr, const int* __restrict__ adj_src,
                        const float* __restrict__ dinv, const unsigned short* __restrict__ hb,
                        const float* __restrict__ s, float* __restrict__ out, int n) {
    int node = blockIdx.x * (blockDim.x >> 6) + (threadIdx.x >> 6);
    int lane = threadIdx.x & 63;
    if (node >= n) return;
    int beg = ptr[node], end = ptr[node + 1];
    float acc = 0.0f;
    int j = beg;
    for (; j + 4 <= end; j += 4) {
        int s0 = adj_src[j + 0], s1 = adj_src[j + 1], s2 = adj_src[j + 2], s3 = adj_src[j + 3];
        float w0 = dinv[s0], w1 = dinv[s1], w2 = dinv[s2], w3 = dinv[s3];
        float x0 = bf2f(hb[(long)s0 * 64 + lane]);
        float x1 = bf2f(hb[(long)s1 * 64 + lane]);
        float x2 = bf2f(hb[(long)s2 * 64 + lane]);
        float x3 = bf2f(hb[(long)s3 * 64 + lane]);
        acc += w0 * x0 + w1 * x1 + w2 * x2 + w3 * x3;
    }
    for (; j < end; ++j) acc += dinv[adj_src[j]] * bf2f(hb[(long)adj_src[j] * 64 + lane]);
    long o = (long)node * 64 + lane;
    out[o] = s[o] + dinv[node] * acc;
}

extern "C" void kernel_launch(void* const* d_in, const int* in_sizes, int n_in,
                              void* d_out, int out_size, void* d_ws, size_t ws_size,
                              hipStream_t stream) {
    const int*   edge_index = (const int*)d_in[1];
    const float* features   = (const float*)d_in[2];
    const float* preference = (const float*)d_in[3];
    const float* W1         = (const float*)d_in[4];
    const float* b1         = (const float*)d_in[5];
    const float* W2         = (const float*)d_in[6];
    const float* b2         = (const float*)d_in[7];

    const int E = in_sizes[1] / 2;                 // 4M directed edges
    const int* e_row = edge_index;
    const int* e_col = edge_index + E;

    // workspace layout (4-byte units)
    float* ws     = (float*)d_ws;
    float* x      = ws;                                    // NNODE*64 (x, then s=x+h)
    unsigned short* xb = (unsigned short*)(x + (size_t)NNODE * 64);   // NNODE*64 bf16
    unsigned short* hb = xb + (size_t)NNODE * 64;                     // NNODE*64 bf16
    float* dinv   = (float*)(hb + (size_t)NNODE * 64);     // NNODE
    int*   cnt    = (int*)(dinv + NNODE);                  // NNODE
    int*   ptr    = cnt + NNODE;                           // NNODE+1
    int*   cursor = ptr + NNODE + 1;                       // NNODE
    int*   bsum   = cursor + NNODE;                        // 128
    float* regionR = (float*)(bsum + 128);                 // shared region
    // MLP phase (dead after GEMM2):
    unsigned short* midb = (unsigned short*)regionR;                 // N_ITEM*256 bf16
    unsigned short* W1t  = midb + (size_t)N_ITEM * D_HID;            // 256*1280 bf16
    unsigned short* W2t  = W1t + (size_t)D_HID * D_FEAT;             // 64*256 bf16
    // Graph phase (overlays MLP phase):
    int*   adj_src = (int*)regionR;                        // E

    float* out_xhat = (float*)d_out;                       // NNODE*64
    float* out_pref = (float*)d_out + (size_t)NNODE * 64;  // N_USER*64

    const int nscan_blocks = (NNODE + 1023) / 1024;        // 98
    const int nchunks = 256;
    const int CH = (E + nchunks - 1) / nchunks;            // edges per chunk

    // --- degree / dinv (XCD-confined histogram) ---
    hipMemsetAsync(cnt, 0, sizeof(int) * NNODE, stream);
    k_count_deg_x<<<nchunks * NXCD, 256, 0, stream>>>(e_row, cnt, E, CH);
    k_dinv<<<(NNODE + 255) / 256, 256, 0, stream>>>(cnt, dinv, NNODE);

    // --- weight transpose + cast ---
    {
        dim3 g1((D_FEAT + 255) / 256, D_HID);
        k_transpose_cast<<<g1, 256, 0, stream>>>(W1, W1t, D_FEAT, D_HID);
        dim3 g2(1, D_LAT);
        k_transpose_cast<<<g2, 256, 0, stream>>>(W2, W2t, D_HID, D_LAT);
    }

    // --- GEMM1: midb = bf16(lrelu(features @ W1 + b1))  [50000 x 256] ---
    k_mfma_gemm<1, 4, true, true, true, false><<<(N_ITEM + 63) / 64, 256, 0, stream>>>(
        features, W1t, b1, midb, nullptr, N_ITEM, D_FEAT, D_HID, 0);

    // --- GEMM2 + fused normalize: x[N_USER..], xb[N_USER..] ---
    k_mfma_gemm<4, 1, false, false, false, true><<<(N_ITEM + 255) / 256, 256, 0, stream>>>(
        midb, W2t, b2, x, xb, N_ITEM, D_HID, D_LAT, N_USER);

    // --- preference rows: normalize into x + xb ---
    k_norm_pref<<<(N_USER + 3) / 4, 256, 0, stream>>>(preference, x, xb, N_USER);

    // --- CSR build ---
    hipMemsetAsync(ptr, 0, sizeof(int), stream);           // ptr[0] = 0
    k_scan_block<<<nscan_blocks, 256, 0, stream>>>(cnt, ptr + 1, bsum, NNODE);
    k_scan_top<<<1, 64, 0, stream>>>(bsum, nscan_blocks);
    k_scan_apply<<<(NNODE + 255) / 256, 256, 0, stream>>>(ptr + 1, cursor, cnt, bsum, NNODE);
    k_build_adj_x<<<nchunks * NXCD, 256, 0, stream>>>(e_row, e_col, cursor, adj_src, E, CH);

    // --- conv1: x <- x + h ; hb = bf16(h) ---
    k_conv1<<<(NNODE + 3) / 4, 256, 0, stream>>>(ptr, adj_src, dinv, xb, x, hb, NNODE);
    // --- conv2: out = (x + h) + conv(h) ---
    k_conv2<<<(NNODE + 3) / 4, 256, 0, stream>>>(ptr, adj_src, dinv, hb, x, out_xhat, NNODE);
    // --- preference passthrough ---
    hipMemcpyAsync(out_pref, preference, sizeof(float) * (size_t)N_USER * 64,
                   hipMemcpyDeviceToDevice, stream);
}